// Round 5
// baseline (3132.369 us; speedup 1.0000x reference)
//
#include <hip/hip_runtime.h>
#include <hip/hip_bf16.h>
#include <hip/hip_cooperative_groups.h>

namespace cg = cooperative_groups;

#define L_NUM 20
#define CC 128
#define TB 8192
#define BB 8
#define TT 64

#define NCONV (L_NUM * 3 * 256 * 128)
#define NMAT  (L_NUM * 128 * 128)
#define XN    ((size_t)BB * TB * CC)   // elements per bf16 x plane

typedef __attribute__((ext_vector_type(4))) float f32x4;
typedef __attribute__((ext_vector_type(8))) short bf16x8;
typedef unsigned int u32;

#define MFMA16 __builtin_amdgcn_mfma_f32_16x16x32_bf16

__device__ __forceinline__ unsigned short f2b(float f) {
  union { __hip_bfloat16 h; unsigned short u; } cv;
  cv.h = __float2bfloat16(f);
  return cv.u;
}
__device__ __forceinline__ float b2fu(u32 u) {
  union { u32 u; float f; } cv;
  cv.u = u << 16;
  return cv.f;
}

// byte offset into a [64 t][128 c] bf16 LDS tile, XOR-swizzled (G4)
__device__ __forceinline__ int swz(int t, int cbyte) {
  return (t * 256 + cbyte) ^ ((t & 7) << 4);
}

// async global->LDS, 16B per lane; LDS dest = wave-uniform base + lane*16
__device__ __forceinline__ void gload16(const void* g, void* l) {
  __builtin_amdgcn_global_load_lds(
      (const __attribute__((address_space(1))) u32*)g,
      (__attribute__((address_space(3))) u32*)l, 16, 0, 0);
}

__global__ void prep_kernel(const float* __restrict__ Wconv,
                            const float* __restrict__ Wout,
                            const float* __restrict__ Wskip,
                            unsigned short* __restrict__ wc,
                            unsigned short* __restrict__ wo,
                            unsigned short* __restrict__ wsk,
                            unsigned short* __restrict__ zp) {
  int i = blockIdx.x * 256 + threadIdx.x;
  if (i < 128) zp[i] = 0;
  if (i < NCONV) {
    // dst [l][k][o][c] <- src [l][o][c][k]
    int c = i & 127;
    int o = (i >> 7) & 255;
    int lk = i >> 15;
    int k = lk % 3;
    int l = lk / 3;
    wc[i] = f2b(Wconv[((size_t)(l * 256 + o) * 128 + c) * 3 + k]);
  }
  if (i < NMAT) {
    wo[i]  = f2b(Wout[i]);
    wsk[i] = f2b(Wskip[i]);
  }
}

// x0 f32 [B][C][T] -> hi/lo bf16 [B][T][C] (plain linear layout)
__global__ __launch_bounds__(256) void x0t_kernel(const float* __restrict__ x0,
                                                  unsigned short* __restrict__ hi,
                                                  unsigned short* __restrict__ lo) {
  __shared__ unsigned short Hs[TT * CC], Ls[TT * CC];
  const int tid = threadIdx.x, lane = tid & 63, w = tid >> 6;
  const int b = blockIdx.y, t0 = blockIdx.x * TT;
  const float* xb = x0 + (size_t)b * CC * TB;
#pragma unroll
  for (int it = 0; it < 8; ++it) {
    int c0 = it * 16 + w * 4;
    u32 hu[4], lu[4];
#pragma unroll
    for (int i2 = 0; i2 < 4; ++i2) {
      float v = xb[(size_t)(c0 + i2) * TB + t0 + lane];
      unsigned short h = f2b(v);
      hu[i2] = h;
      lu[i2] = f2b(v - b2fu(h));
    }
    uint2 hp, lp;
    hp.x = hu[0] | (hu[1] << 16); hp.y = hu[2] | (hu[3] << 16);
    lp.x = lu[0] | (lu[1] << 16); lp.y = lu[2] | (lu[3] << 16);
    *reinterpret_cast<uint2*>(reinterpret_cast<char*>(Hs) + swz(lane, c0 * 2)) = hp;
    *reinterpret_cast<uint2*>(reinterpret_cast<char*>(Ls) + swz(lane, c0 * 2)) = lp;
  }
  __syncthreads();
  unsigned short* hb = hi + ((size_t)b * TB + t0) * CC;
  unsigned short* lb = lo + ((size_t)b * TB + t0) * CC;
#pragma unroll
  for (int it = 0; it < 4; ++it) {
    int o = it * 4096 + tid * 16;
    int t = o >> 8;
    int cl = o & 255;
    int li = t * 256 + (cl ^ ((t & 7) << 4));
    *reinterpret_cast<f32x4*>(reinterpret_cast<char*>(hb) + (size_t)t * 256 + cl) =
        *reinterpret_cast<f32x4*>(reinterpret_cast<char*>(Hs) + li);
    *reinterpret_cast<f32x4*>(reinterpret_cast<char*>(lb) + (size_t)t * 256 + cl) =
        *reinterpret_cast<f32x4*>(reinterpret_cast<char*>(Ls) + li);
  }
}

// One cooperative kernel for all 20 layers. 256 blocks (1/CU), 512 threads.
// Each block owns a 256-t supertile of one batch: 4 tiles of 64 t.
// lo residual lives in registers across layers; hi planes ping-pong in global.
__global__ __launch_bounds__(512, 2) void stack_kernel(
    unsigned short* __restrict__ hA,          // ws plane
    unsigned short* __restrict__ hB,          // d_out-aliased plane
    const unsigned short* __restrict__ lo0,   // x0 lo plane (read once)
    const unsigned short* __restrict__ zpage, // 256B zeros
    const unsigned short* __restrict__ wc,    // [L][3][256][128] bf16
    const float* __restrict__ bconv_a,        // [L][256]
    const unsigned short* __restrict__ wo,    // [L][128][128]
    const float* __restrict__ bout_a,         // [L][128]
    const unsigned short* __restrict__ wsk,   // [L][128][128]
    const float* __restrict__ bskip_a,        // [L][128]
    float* __restrict__ skips,                // [L][B][S][T] f32
    float* __restrict__ fx) {                 // [B][C][T] f32
  __shared__ unsigned short Xs[2][3][TT * CC];  // double-buffered taps, 96 KB

  const int tid = threadIdx.x;
  const int lane = tid & 63;
  const int w = tid >> 6;          // wave 0..7
  const int lo16 = lane & 15;
  const int hi4 = lane >> 4;
  const int cB = w * 16 + hi4 * 4; // this thread's 4 output channels

  const int bid = blockIdx.x;
  const int b = (bid >> 3) >> 2;                              // batch 0..7
  const int st0 = (bid & 7) * 1024 + ((bid >> 3) & 3) * 256;  // supertile t base

  // persistent lo-residual registers: [tile][j] (statically indexed only)
  uint2 lres[4][4];
#pragma unroll
  for (int i = 0; i < 4; ++i)
#pragma unroll
    for (int j = 0; j < 4; ++j)
      lres[i][j] = *reinterpret_cast<const uint2*>(
          lo0 + ((size_t)b * TB + st0 + i * 64 + j * 16 + lo16) * CC + cB);

  auto STAGE = [&](const unsigned short* hbp, int t0_, int bufsel, int dil_) {
#pragma unroll
    for (int k = 0; k < 3; ++k) {
      int tbase = t0_ + (k - 2) * dil_;
#pragma unroll
      for (int ii = 0; ii < 2; ++ii) {
        int o = w * 2048 + ii * 1024 + lane * 16;
        int tl = o >> 8;
        int cb = (o & 255) ^ ((tl & 7) << 4);
        int tg = tbase + tl;
        const char* src = (tg >= 0)
            ? (reinterpret_cast<const char*>(hbp + (size_t)tg * CC) + cb)
            : (reinterpret_cast<const char*>(zpage) + cb);
        gload16(src,
                reinterpret_cast<char*>(&Xs[bufsel][k][0]) + w * 2048 + ii * 1024);
      }
    }
  };

  // prologue: stage layer-0 tile-0 (input plane hB, dil=1)
  STAGE(hB + (size_t)b * TB * CC, st0, 0, 1);

  for (int l = 0; l < L_NUM; ++l) {
    const int dil = 1 << (l % 10);
    const unsigned short* hb = ((l & 1) ? hA : hB) + (size_t)b * TB * CC;
    unsigned short* ho = ((l & 1) ? hB : hA) + (size_t)b * TB * CC;
    const int last = (l == L_NUM - 1);
    const unsigned short* Wc_l = wc + (size_t)l * 3 * 256 * 128;
    const unsigned short* Wo_l = wo + (size_t)l * 128 * 128;
    const unsigned short* Ws_l = wsk + (size_t)l * 128 * 128;
    float* skb = skips + (size_t)l * XN + (size_t)b * CC * TB;
    float* fxb = fx + (size_t)b * CC * TB;

    f32x4 bca = *reinterpret_cast<const f32x4*>(bconv_a + l * 256 + cB);
    f32x4 bcg = *reinterpret_cast<const f32x4*>(bconv_a + l * 256 + 128 + cB);
    f32x4 bsk = *reinterpret_cast<const f32x4*>(bskip_a + l * 128 + cB);
    f32x4 bo  = *reinterpret_cast<const f32x4*>(bout_a + l * 128 + cB);

#pragma unroll
    for (int i = 0; i < 4; ++i) {
      const int cur = i & 1;
      const int t0 = st0 + i * 64;

      // taps for tile i ready (they were the only loads left in flight)
      asm volatile("s_waitcnt vmcnt(0)" ::: "memory");
      __builtin_amdgcn_s_barrier();
      __builtin_amdgcn_sched_barrier(0);
      asm volatile("" ::: "memory");

      // prefetch tile i+1 into the other buffer (overlaps GEMM1+GEMM2)
      if (i < 3) STAGE(hb, st0 + (i + 1) * 64, cur ^ 1, dil);

      // ---- conv GEMM: rows cB.. of A-half and G-half
      f32x4 zero4 = {0.f, 0.f, 0.f, 0.f};
      f32x4 accA[4], accG[4];
#pragma unroll
      for (int j = 0; j < 4; ++j) { accA[j] = zero4; accG[j] = zero4; }

#pragma unroll
      for (int k = 0; k < 3; ++k) {
        const unsigned short* Wk = Wc_l + k * 256 * 128;
#pragma unroll
        for (int kk = 0; kk < 4; ++kk) {
          int c0 = kk * 32 + hi4 * 8;
          bf16x8 aA = *reinterpret_cast<const bf16x8*>(Wk + (w * 16 + lo16) * 128 + c0);
          bf16x8 aG = *reinterpret_cast<const bf16x8*>(Wk + (128 + w * 16 + lo16) * 128 + c0);
#pragma unroll
          for (int j = 0; j < 4; ++j) {
            bf16x8 bx8 = *reinterpret_cast<const bf16x8*>(
                reinterpret_cast<const char*>(&Xs[cur][k][0]) + swz(j * 16 + lo16, c0 * 2));
            accA[j] = MFMA16(aA, bx8, accA[j], 0, 0, 0);
            accG[j] = MFMA16(aG, bx8, accG[j], 0, 0, 0);
          }
        }
      }

      // ---- gated activation into registers
      uint2 zpk[4];
#pragma unroll
      for (int j = 0; j < 4; ++j) {
        u32 zu[4];
#pragma unroll
        for (int reg = 0; reg < 4; ++reg) {
          float a = accA[j][reg] + bca[reg];
          float g = accG[j][reg] + bcg[reg];
          float ea = __builtin_amdgcn_exp2f(2.885390081777927f * a);   // e^{2a}
          float th = 1.f - 2.f * __builtin_amdgcn_rcpf(1.f + ea);       // tanh(a)
          float sg = __builtin_amdgcn_rcpf(
              1.f + __builtin_amdgcn_exp2f(-1.4426950408889634f * g));  // sigmoid
          zu[reg] = f2b(th * sg);
        }
        zpk[j].x = zu[0] | (zu[1] << 16);
        zpk[j].y = zu[2] | (zu[3] << 16);
      }

      // all GEMM1 tap0 reads done before z overlays tap0
      asm volatile("" ::: "memory");
      __builtin_amdgcn_s_barrier();
      __builtin_amdgcn_sched_barrier(0);
      asm volatile("" ::: "memory");

#pragma unroll
      for (int j = 0; j < 4; ++j)
        *reinterpret_cast<uint2*>(reinterpret_cast<char*>(&Xs[cur][0][0]) +
                                  swz(j * 16 + lo16, cB * 2)) = zpk[j];

      asm volatile("s_waitcnt lgkmcnt(0)" ::: "memory");
      __builtin_amdgcn_s_barrier();
      __builtin_amdgcn_sched_barrier(0);
      asm volatile("" ::: "memory");

      // ---- skip/out GEMMs
      f32x4 accS[4], accO[4];
#pragma unroll
      for (int j = 0; j < 4; ++j) { accS[j] = zero4; accO[j] = zero4; }

#pragma unroll
      for (int kk = 0; kk < 4; ++kk) {
        int c0 = kk * 32 + hi4 * 8;
        bf16x8 aS = *reinterpret_cast<const bf16x8*>(Ws_l + (w * 16 + lo16) * 128 + c0);
        bf16x8 aO = *reinterpret_cast<const bf16x8*>(Wo_l + (w * 16 + lo16) * 128 + c0);
#pragma unroll
        for (int j = 0; j < 4; ++j) {
          bf16x8 bz = *reinterpret_cast<const bf16x8*>(
              reinterpret_cast<const char*>(&Xs[cur][0][0]) + swz(j * 16 + lo16, c0 * 2));
          accS[j] = MFMA16(aS, bz, accS[j], 0, 0, 0);
          accO[j] = MFMA16(aO, bz, accO[j], 0, 0, 0);
        }
      }

      // ---- epilogue: skip store; residual add (hi from tap2 LDS, lo from regs)
#pragma unroll
      for (int j = 0; j < 4; ++j) {
        int t = j * 16 + lo16;
        uint2 hp = *reinterpret_cast<const uint2*>(
            reinterpret_cast<const char*>(&Xs[cur][2][0]) + swz(t, cB * 2));
        u32 hu[4] = {hp.x & 0xffffu, hp.x >> 16, hp.y & 0xffffu, hp.y >> 16};
        u32 lu[4] = {lres[i][j].x & 0xffffu, lres[i][j].x >> 16,
                     lres[i][j].y & 0xffffu, lres[i][j].y >> 16};
#pragma unroll
        for (int reg = 0; reg < 4; ++reg)
          skb[(size_t)(cB + reg) * TB + t0 + t] = accS[j][reg] + bsk[reg];
        if (last) {
          uint2 zp2 = *reinterpret_cast<const uint2*>(
              reinterpret_cast<const char*>(&Xs[cur][0][0]) + swz(t, cB * 2));
          u32 zu[4] = {zp2.x & 0xffffu, zp2.x >> 16, zp2.y & 0xffffu, zp2.y >> 16};
#pragma unroll
          for (int reg = 0; reg < 4; ++reg)
            fxb[(size_t)(cB + reg) * TB + t0 + t] =
                b2fu(zu[reg]) + b2fu(hu[reg]) + b2fu(lu[reg]);
        } else {
          u32 hn[4], ln[4];
#pragma unroll
          for (int reg = 0; reg < 4; ++reg) {
            float v = accO[j][reg] + bo[reg] + b2fu(hu[reg]) + b2fu(lu[reg]);
            unsigned short h = f2b(v);
            hn[reg] = h;
            ln[reg] = f2b(v - b2fu(h));
          }
          uint2 hq;
          hq.x = hn[0] | (hn[1] << 16); hq.y = hn[2] | (hn[3] << 16);
          *reinterpret_cast<uint2*>(ho + (size_t)(t0 + t) * CC + cB) = hq;
          lres[i][j].x = ln[0] | (ln[1] << 16);
          lres[i][j].y = ln[2] | (ln[3] << 16);
        }
      }
    }  // tiles

    if (!last) {
      __threadfence();
      cg::this_grid().sync();
      const unsigned short* hbn = (((l + 1) & 1) ? hA : hB) + (size_t)b * TB * CC;
      STAGE(hbn, st0, 0, 1 << ((l + 1) % 10));
    }
  }  // layers
}

extern "C" void kernel_launch(void* const* d_in, const int* in_sizes, int n_in,
                              void* d_out, int out_size, void* d_ws, size_t ws_size,
                              hipStream_t stream) {
  const float* x0    = (const float*)d_in[0];
  const float* Wconv = (const float*)d_in[1];
  const float* bconv = (const float*)d_in[2];
  const float* Wout  = (const float*)d_in[3];
  const float* bout  = (const float*)d_in[4];
  const float* Wskip = (const float*)d_in[5];
  const float* bskip = (const float*)d_in[6];

  unsigned short* wc  = (unsigned short*)d_ws;   // [L][3][256][128] bf16
  unsigned short* wo  = wc + NCONV;              // [L][128][128] bf16
  unsigned short* wsk = wo + NMAT;               // [L][128][128] bf16
  unsigned short* zp  = wsk + NMAT;              // 256B zero page
  unsigned short* hA  = zp + 128;                // [B][T][C] bf16 hi plane A (ws)
  unsigned short* lo  = hA + XN;                 // [B][T][C] bf16 x0 lo plane

  float* fx = (float*)d_out;                      // final x region [B][C][T] f32
  float* skips = fx + XN;                         // [L][B][S][T] f32
  unsigned short* hB = (unsigned short*)d_out;    // hi plane B aliased in fx region
  // parity: x0t->hB; even layers read hB write hA; odd read hA write hB.
  // l19 (odd) reads hA and writes f32 over hB's region after hB is dead.

  prep_kernel<<<(NCONV + 255) / 256, 256, 0, stream>>>(Wconv, Wout, Wskip, wc, wo, wsk, zp);
  x0t_kernel<<<dim3(TB / TT, BB), 256, 0, stream>>>(x0, hB, lo);

  void* args[] = {(void*)&hA, (void*)&hB, (void*)&lo, (void*)&zp,
                  (void*)&wc, (void*)&bconv, (void*)&wo, (void*)&bout,
                  (void*)&wsk, (void*)&bskip, (void*)&skips, (void*)&fx};
  hipLaunchCooperativeKernel((const void*)stack_kernel, dim3(256), dim3(512),
                             args, 0, stream);
}

// Round 6
// 1536.578 us; speedup vs baseline: 2.0385x; 2.0385x over previous
//
#include <hip/hip_runtime.h>
#include <hip/hip_bf16.h>

#define L_NUM 20
#define CC 128
#define TB 8192
#define BB 8
#define TT 32

#define NCONV (L_NUM * 3 * 256 * 128)
#define NMAT  (L_NUM * 128 * 128)
#define XN    ((size_t)BB * TB * CC)   // elements per bf16 x plane

typedef __attribute__((ext_vector_type(4))) float f32x4;
typedef __attribute__((ext_vector_type(8))) short bf16x8;
typedef unsigned int u32;

#define MFMA16 __builtin_amdgcn_mfma_f32_16x16x32_bf16

static const int DILS[L_NUM] = {1, 2, 4, 8, 16, 32, 64, 128, 256, 512,
                                1, 2, 4, 8, 16, 32, 64, 128, 256, 512};

__device__ __forceinline__ unsigned short f2b(float f) {
  union { __hip_bfloat16 h; unsigned short u; } cv;
  cv.h = __float2bfloat16(f);
  return cv.u;
}
__device__ __forceinline__ float b2fu(u32 u) {
  union { u32 u; float f; } cv;
  cv.u = u << 16;
  return cv.f;
}

// byte offset into a [T t][128 c] bf16 LDS tile, XOR-swizzled (G4)
__device__ __forceinline__ int swz(int t, int cbyte) {
  return (t * 256 + cbyte) ^ ((t & 7) << 4);
}

// async global->LDS, 16B per lane; LDS dest = wave-uniform base + lane*16
__device__ __forceinline__ void gload16(const void* g, void* l) {
  __builtin_amdgcn_global_load_lds(
      (const __attribute__((address_space(1))) u32*)g,
      (__attribute__((address_space(3))) u32*)l, 16, 0, 0);
}

__global__ void prep_kernel(const float* __restrict__ Wconv,
                            const float* __restrict__ Wout,
                            const float* __restrict__ Wskip,
                            unsigned short* __restrict__ wc,
                            unsigned short* __restrict__ wo,
                            unsigned short* __restrict__ wsk,
                            unsigned short* __restrict__ zp) {
  int i = blockIdx.x * 256 + threadIdx.x;
  if (i < 128) zp[i] = 0;
  if (i < NCONV) {
    // dst [l][k][o][c] <- src [l][o][c][k]
    int c = i & 127;
    int o = (i >> 7) & 255;
    int lk = i >> 15;
    int k = lk % 3;
    int l = lk / 3;
    wc[i] = f2b(Wconv[((size_t)(l * 256 + o) * 128 + c) * 3 + k]);
  }
  if (i < NMAT) {
    wo[i]  = f2b(Wout[i]);
    wsk[i] = f2b(Wskip[i]);
  }
}

// x0 f32 [B][C][T] -> hi/lo bf16 [B][T][C] (plain linear layout)
__global__ __launch_bounds__(256) void x0t_kernel(const float* __restrict__ x0,
                                                  unsigned short* __restrict__ hi,
                                                  unsigned short* __restrict__ lo) {
  __shared__ unsigned short Hs[64 * CC], Ls[64 * CC];
  const int tid = threadIdx.x, lane = tid & 63, w = tid >> 6;
  const int b = blockIdx.y, t0 = blockIdx.x * 64;
  const float* xb = x0 + (size_t)b * CC * TB;
#pragma unroll
  for (int it = 0; it < 8; ++it) {
    int c0 = it * 16 + w * 4;
    u32 hu[4], lu[4];
#pragma unroll
    for (int i2 = 0; i2 < 4; ++i2) {
      float v = xb[(size_t)(c0 + i2) * TB + t0 + lane];
      unsigned short h = f2b(v);
      hu[i2] = h;
      lu[i2] = f2b(v - b2fu(h));
    }
    uint2 hp, lp;
    hp.x = hu[0] | (hu[1] << 16); hp.y = hu[2] | (hu[3] << 16);
    lp.x = lu[0] | (lu[1] << 16); lp.y = lu[2] | (lu[3] << 16);
    *reinterpret_cast<uint2*>(reinterpret_cast<char*>(Hs) + swz(lane, c0 * 2)) = hp;
    *reinterpret_cast<uint2*>(reinterpret_cast<char*>(Ls) + swz(lane, c0 * 2)) = lp;
  }
  __syncthreads();
  unsigned short* hb = hi + ((size_t)b * TB + t0) * CC;
  unsigned short* lb = lo + ((size_t)b * TB + t0) * CC;
#pragma unroll
  for (int it = 0; it < 4; ++it) {
    int o = it * 4096 + tid * 16;
    int t = o >> 8;
    int cl = o & 255;
    int li = t * 256 + (cl ^ ((t & 7) << 4));
    *reinterpret_cast<f32x4*>(reinterpret_cast<char*>(hb) + (size_t)t * 256 + cl) =
        *reinterpret_cast<f32x4*>(reinterpret_cast<char*>(Hs) + li);
    *reinterpret_cast<f32x4*>(reinterpret_cast<char*>(lb) + (size_t)t * 256 + cl) =
        *reinterpret_cast<f32x4*>(reinterpret_cast<char*>(Ls) + li);
  }
}

// Per-layer kernel, occupancy-tuned: TT=32, 2048 blocks, 4 waves, <=102 VGPR.
// Wave w owns conv rows [32w,32w+32) of A-half and G-half (2 frags of 16),
// and the same 32 rows of the skip/out GEMMs. t covered by 2 j-frags of 16.
__global__ __launch_bounds__(256, 5) void layer_kernel(
    const unsigned short* __restrict__ hin,   // [B][T][C] bf16 hi plane
    unsigned short* __restrict__ hout,        // (unused if last)
    unsigned short* __restrict__ lob,         // [B][T][C] bf16 lo plane
    const unsigned short* __restrict__ zpage, // 256B zeros
    const unsigned short* __restrict__ Wc,    // [3][256][128] bf16
    const float* __restrict__ bconv,          // [256]
    const unsigned short* __restrict__ Wo,    // [128][128] bf16
    const float* __restrict__ bout,           // [128]
    const unsigned short* __restrict__ Wsk,   // [128][128] bf16
    const float* __restrict__ bskip,          // [128]
    float* __restrict__ skipo,                // [B][S][T] f32 slice
    float* __restrict__ fxout,                // [B][C][T] f32 (last only)
    int dil, int last) {
  __shared__ unsigned short Xs[3][TT * CC];  // 3 tap tiles, 8 KB each
  unsigned short* Zs = &Xs[0][0];            // z overlays tap0 (barriered)

  const int tid = threadIdx.x;
  const int lane = tid & 63;
  const int w = tid >> 6;          // wave 0..3
  const int lo16 = lane & 15;
  const int hi4 = lane >> 4;

  // XCD-aware remap: each XCD owns a contiguous 1024-t window (all batches)
  int p = blockIdx.x;              // 0..255 tile index
  int xcd = p & 7, ii = p >> 3;
  int t0 = (xcd * 32 + ii) * TT;
  int b = blockIdx.y;

  const unsigned short* hb = hin + (size_t)b * TB * CC;

  // ---- stage 3 taps via global_load_lds (linear LDS, pre-swizzled source)
#pragma unroll
  for (int k = 0; k < 3; ++k) {
    int tbase = t0 + (k - 2) * dil;
#pragma unroll
    for (int i = 0; i < 2; ++i) {
      int o = (w * 2 + i) * 1024 + lane * 16;   // byte offset in 8KB tile
      int tl = o >> 8;
      int cb = (o & 255) ^ ((tl & 7) << 4);
      int tg = tbase + tl;
      const char* src = (tg >= 0)
          ? (reinterpret_cast<const char*>(hb + (size_t)tg * CC) + cb)
          : (reinterpret_cast<const char*>(zpage) + cb);
      gload16(src, reinterpret_cast<char*>(&Xs[k][0]) + (w * 2 + i) * 1024);
    }
  }

  // lo-residual prefetch (overlaps stage; consumed in epilogue)
  const unsigned short* lb = lob + (size_t)b * TB * CC;
  uint2 lres[2][2];
#pragma unroll
  for (int r = 0; r < 2; ++r)
#pragma unroll
    for (int j = 0; j < 2; ++j)
      lres[r][j] = *reinterpret_cast<const uint2*>(
          lb + (size_t)(t0 + j * 16 + lo16) * CC + w * 32 + r * 16 + hi4 * 4);

  __syncthreads();  // bar1: taps resident

  // ---- conv GEMM
  f32x4 zero4 = {0.f, 0.f, 0.f, 0.f};
  f32x4 accA[2][2], accG[2][2];
#pragma unroll
  for (int r = 0; r < 2; ++r)
#pragma unroll
    for (int j = 0; j < 2; ++j) { accA[r][j] = zero4; accG[r][j] = zero4; }

#pragma unroll
  for (int k = 0; k < 3; ++k) {
    const unsigned short* Wk = Wc + k * 256 * 128;
#pragma unroll
    for (int kk = 0; kk < 4; ++kk) {
      int c0 = kk * 32 + hi4 * 8;
      bf16x8 aA0 = *reinterpret_cast<const bf16x8*>(Wk + (w * 32 + lo16) * 128 + c0);
      bf16x8 aA1 = *reinterpret_cast<const bf16x8*>(Wk + (w * 32 + 16 + lo16) * 128 + c0);
      bf16x8 aG0 = *reinterpret_cast<const bf16x8*>(Wk + (128 + w * 32 + lo16) * 128 + c0);
      bf16x8 aG1 = *reinterpret_cast<const bf16x8*>(Wk + (128 + w * 32 + 16 + lo16) * 128 + c0);
#pragma unroll
      for (int j = 0; j < 2; ++j) {
        bf16x8 bx8 = *reinterpret_cast<const bf16x8*>(
            reinterpret_cast<const char*>(&Xs[k][0]) + swz(j * 16 + lo16, c0 * 2));
        accA[0][j] = MFMA16(aA0, bx8, accA[0][j], 0, 0, 0);
        accA[1][j] = MFMA16(aA1, bx8, accA[1][j], 0, 0, 0);
        accG[0][j] = MFMA16(aG0, bx8, accG[0][j], 0, 0, 0);
        accG[1][j] = MFMA16(aG1, bx8, accG[1][j], 0, 0, 0);
      }
    }
  }

  // ---- gated activation into registers (rcp/exp2 form)
  uint2 zpk[2][2];
#pragma unroll
  for (int r = 0; r < 2; ++r) {
    f32x4 bca = *reinterpret_cast<const f32x4*>(bconv + w * 32 + r * 16 + hi4 * 4);
    f32x4 bcg = *reinterpret_cast<const f32x4*>(bconv + 128 + w * 32 + r * 16 + hi4 * 4);
#pragma unroll
    for (int j = 0; j < 2; ++j) {
      u32 zu[4];
#pragma unroll
      for (int reg = 0; reg < 4; ++reg) {
        float a = accA[r][j][reg] + bca[reg];
        float g = accG[r][j][reg] + bcg[reg];
        float ea = __builtin_amdgcn_exp2f(2.885390081777927f * a);   // e^{2a}
        float th = 1.f - 2.f * __builtin_amdgcn_rcpf(1.f + ea);       // tanh(a)
        float sg = __builtin_amdgcn_rcpf(
            1.f + __builtin_amdgcn_exp2f(-1.4426950408889634f * g));  // sigmoid
        zu[reg] = f2b(th * sg);
      }
      zpk[r][j].x = zu[0] | (zu[1] << 16);
      zpk[r][j].y = zu[2] | (zu[3] << 16);
    }
  }

  __syncthreads();  // bar2: all GEMM1 tap0 reads complete

  // z write: channels cB..cB+3 at t = j*16+lo16 (overlays tap0)
#pragma unroll
  for (int r = 0; r < 2; ++r)
#pragma unroll
    for (int j = 0; j < 2; ++j)
      *reinterpret_cast<uint2*>(reinterpret_cast<char*>(Zs) +
          swz(j * 16 + lo16, (w * 32 + r * 16 + hi4 * 4) * 2)) = zpk[r][j];
  __syncthreads();  // bar3: z tile complete

  // ---- skip/out GEMMs: rows [32w,32w+32) of S and O
  f32x4 accS[2][2], accO[2][2];
#pragma unroll
  for (int r = 0; r < 2; ++r)
#pragma unroll
    for (int j = 0; j < 2; ++j) { accS[r][j] = zero4; accO[r][j] = zero4; }

#pragma unroll
  for (int kk = 0; kk < 4; ++kk) {
    int c0 = kk * 32 + hi4 * 8;
    bf16x8 aS0 = *reinterpret_cast<const bf16x8*>(Wsk + (w * 32 + lo16) * 128 + c0);
    bf16x8 aS1 = *reinterpret_cast<const bf16x8*>(Wsk + (w * 32 + 16 + lo16) * 128 + c0);
    bf16x8 aO0 = *reinterpret_cast<const bf16x8*>(Wo + (w * 32 + lo16) * 128 + c0);
    bf16x8 aO1 = *reinterpret_cast<const bf16x8*>(Wo + (w * 32 + 16 + lo16) * 128 + c0);
#pragma unroll
    for (int j = 0; j < 2; ++j) {
      bf16x8 bz = *reinterpret_cast<const bf16x8*>(
          reinterpret_cast<const char*>(Zs) + swz(j * 16 + lo16, c0 * 2));
      accS[0][j] = MFMA16(aS0, bz, accS[0][j], 0, 0, 0);
      accS[1][j] = MFMA16(aS1, bz, accS[1][j], 0, 0, 0);
      accO[0][j] = MFMA16(aO0, bz, accO[0][j], 0, 0, 0);
      accO[1][j] = MFMA16(aO1, bz, accO[1][j], 0, 0, 0);
    }
  }

  // ---- epilogue: nt skip store; residual add (hi from tap2 LDS, lo from regs)
  float* skb = skipo + (size_t)b * CC * TB;
  float* fxb = fxout + (size_t)b * CC * TB;
  unsigned short* hrow = hout + (size_t)b * TB * CC;
  unsigned short* lrow = lob + (size_t)b * TB * CC;

#pragma unroll
  for (int r = 0; r < 2; ++r) {
    f32x4 bsk = *reinterpret_cast<const f32x4*>(bskip + w * 32 + r * 16 + hi4 * 4);
    f32x4 bo  = *reinterpret_cast<const f32x4*>(bout + w * 32 + r * 16 + hi4 * 4);
#pragma unroll
    for (int j = 0; j < 2; ++j) {
      int t = j * 16 + lo16;
      int cB = w * 32 + r * 16 + hi4 * 4;
      // hi residual from tap2 tile (tap2 window == [t0, t0+TT))
      uint2 hp = *reinterpret_cast<const uint2*>(
          reinterpret_cast<const char*>(&Xs[2][0]) + swz(t, cB * 2));
      u32 hu[4] = {hp.x & 0xffffu, hp.x >> 16, hp.y & 0xffffu, hp.y >> 16};
      u32 lu[4] = {lres[r][j].x & 0xffffu, lres[r][j].x >> 16,
                   lres[r][j].y & 0xffffu, lres[r][j].y >> 16};
#pragma unroll
      for (int reg = 0; reg < 4; ++reg)
        __builtin_nontemporal_store(accS[r][j][reg] + bsk[reg],
                                    skb + (size_t)(cB + reg) * TB + t0 + t);
      if (last) {
        uint2 zp2 = *reinterpret_cast<const uint2*>(
            reinterpret_cast<const char*>(Zs) + swz(t, cB * 2));
        u32 zu[4] = {zp2.x & 0xffffu, zp2.x >> 16, zp2.y & 0xffffu, zp2.y >> 16};
#pragma unroll
        for (int reg = 0; reg < 4; ++reg)
          __builtin_nontemporal_store(b2fu(zu[reg]) + b2fu(hu[reg]) + b2fu(lu[reg]),
                                      fxb + (size_t)(cB + reg) * TB + t0 + t);
      } else {
        u32 hn[4], ln[4];
#pragma unroll
        for (int reg = 0; reg < 4; ++reg) {
          float v = accO[r][j][reg] + bo[reg] + b2fu(hu[reg]) + b2fu(lu[reg]);
          unsigned short h = f2b(v);
          hn[reg] = h;
          ln[reg] = f2b(v - b2fu(h));
        }
        uint2 hq, lq;
        hq.x = hn[0] | (hn[1] << 16); hq.y = hn[2] | (hn[3] << 16);
        lq.x = ln[0] | (ln[1] << 16); lq.y = ln[2] | (ln[3] << 16);
        *reinterpret_cast<uint2*>(hrow + (size_t)(t0 + t) * CC + cB) = hq;
        *reinterpret_cast<uint2*>(lrow + (size_t)(t0 + t) * CC + cB) = lq;
      }
    }
  }
}

extern "C" void kernel_launch(void* const* d_in, const int* in_sizes, int n_in,
                              void* d_out, int out_size, void* d_ws, size_t ws_size,
                              hipStream_t stream) {
  const float* x0    = (const float*)d_in[0];
  const float* Wconv = (const float*)d_in[1];
  const float* bconv = (const float*)d_in[2];
  const float* Wout  = (const float*)d_in[3];
  const float* bout  = (const float*)d_in[4];
  const float* Wskip = (const float*)d_in[5];
  const float* bskip = (const float*)d_in[6];

  unsigned short* wc  = (unsigned short*)d_ws;   // [L][3][256][128] bf16
  unsigned short* wo  = wc + NCONV;              // [L][128][128] bf16
  unsigned short* wsk = wo + NMAT;               // [L][128][128] bf16
  unsigned short* zp  = wsk + NMAT;              // 256B zero page
  unsigned short* hiA = zp + 128;                // [B][T][C] bf16 hi plane A
  unsigned short* lob = hiA + XN;                // [B][T][C] bf16 lo plane

  float* fx = (float*)d_out;                      // final x region [B][C][T]
  float* skips = fx + XN;                         // [L][B][S][T]
  unsigned short* hiB = (unsigned short*)d_out;   // hi plane B aliased in x region
  // parity: x0t->hiB; even layers read hiB write hiA; odd read hiA write hiB.
  // l19 (odd) reads hiA and writes f32 over hiB's region -> no race.

  prep_kernel<<<(NCONV + 255) / 256, 256, 0, stream>>>(Wconv, Wout, Wskip, wc, wo, wsk, zp);
  x0t_kernel<<<dim3(TB / 64, BB), 256, 0, stream>>>(x0, hiB, lob);

  for (int l = 0; l < L_NUM; ++l) {
    const unsigned short* hin = (l % 2 == 0) ? hiB : hiA;
    unsigned short* hout      = (l % 2 == 0) ? hiA : hiB;
    layer_kernel<<<dim3(TB / TT, BB), 256, 0, stream>>>(
        hin, hout, lob, zp,
        wc + (size_t)l * 3 * 256 * 128, bconv + (size_t)l * 256,
        wo + (size_t)l * 128 * 128, bout + (size_t)l * 128,
        wsk + (size_t)l * 128 * 128, bskip + (size_t)l * 128,
        skips + (size_t)l * XN, fx,
        DILS[l], l == L_NUM - 1 ? 1 : 0);
  }
}